// Round 16
// baseline (609.435 us; speedup 1.0000x reference)
//
#include <hip/hip_runtime.h>
#include <hip/hip_bf16.h>

#define N_NODES 20000
#define N_EDGES 100000
#define N_LAYERS 25
#define NPAD 20096   // 157*128
#define EPS_BN 1e-5f
#define LOG2E 1.44269504088896340736f
#define NL_NN (N_LAYERS * N_NODES)          // 500000
#define TOTAL_E (N_LAYERS * N_EDGES)        // 2500000
#define SCAN_BLKS ((NL_NN + 1023) / 1024)   // 489
#define QUARTER_N 5000
#define CNT_BLKS (N_LAYERS * 4)             // 100
#define XLR_BASE CNT_BLKS                   // 100
#define XLR_BLKS (NL_NN / 16)               // 31250
#define W1T_BASE (XLR_BASE + XLR_BLKS)      // 31350
#define PREP_BLKS (W1T_BASE + 700)          // 32050
#define EDGE_BLKS ((TOTAL_E + 1023) / 1024) // 2442
#define FILL_BLKS (EDGE_BLKS + SCAN_BLKS)
#define CHUNK 61
#define ATTN_WAVES ((NL_NN + CHUNK - 1) / CHUNK)   // 8197
#define ATTN_BLKS ((ATTN_WAVES + 3) / 4)           // 2050

typedef short short8 __attribute__((ext_vector_type(8)));
typedef short short4v __attribute__((ext_vector_type(4)));
typedef float floatx4 __attribute__((ext_vector_type(4)));

template <int PAT>
__device__ __forceinline__ float swz(float v) {
  return __int_as_float(__builtin_amdgcn_ds_swizzle(__float_as_int(v), PAT));
}

template <int CTRL>
__device__ __forceinline__ float dpp_add(float v) {
  int r = __builtin_amdgcn_update_dpp(0, __float_as_int(v), CTRL, 0xF, 0xF, true);
  return v + __int_as_float(r);
}

// int index on purpose: 32-bit address math
__device__ __forceinline__ float ldbf(const unsigned short* __restrict__ p, int idx) {
  return __uint_as_float((unsigned)p[idx] << 16);
}

__device__ __forceinline__ unsigned short bfbits(float v) {
  return __builtin_bit_cast(unsigned short, (__hip_bfloat16)v);
}

// async global->LDS, 16B per lane; LDS dest = wave-uniform base + lane*16
__device__ __forceinline__ void gl_lds16(const short* g, short* l) {
  __builtin_amdgcn_global_load_lds(
      (const __attribute__((address_space(1))) void*)g,
      (__attribute__((address_space(3))) void*)l, 16, 0, 0);
}

// --- prep: count (LDS histogram, captures per-edge rank) + xlr + w1t --------
__global__ __launch_bounds__(1024) void prep_kernel(
    const int* __restrict__ ei, const float* __restrict__ x,
    const float* __restrict__ Wl, const float* __restrict__ bl,
    const float* __restrict__ Wr, const float* __restrict__ br,
    const float* __restrict__ W1, int* __restrict__ cnt,
    int* __restrict__ rank,
    unsigned short* __restrict__ xlb, unsigned short* __restrict__ xrb,
    __hip_bfloat16* __restrict__ W1bT) {
  __shared__ int smem[QUARTER_N];  // 20 KB (count hist); w1t reuses as float tile
  int b = blockIdx.x;
  if (b < XLR_BASE) {
    int l = b >> 2, base = (b & 3) * QUARTER_N;
    for (int i = threadIdx.x; i < QUARTER_N; i += 1024) smem[i] = 0;
    __syncthreads();
    const int* dstp = ei + (size_t)l * 2 * N_EDGES + N_EDGES;
    int* rkp = rank + l * N_EDGES;
    for (int e = threadIdx.x; e < N_EDGES; e += 1024) {
      int d = dstp[e] - base;
      if ((unsigned)d < (unsigned)QUARTER_N) rkp[e] = atomicAdd(&smem[d], 1);
    }
    __syncthreads();
    int* outp = cnt + l * N_NODES + base;
    for (int i = threadIdx.x; i < QUARTER_N; i += 1024) outp[i] = smem[i];
  } else if (b < W1T_BASE) {
    int wid = (b - XLR_BASE) * 16 + (threadIdx.x >> 6);
    int lane = threadIdx.x & 63;
    int l = wid / N_NODES, n = wid - l * N_NODES;
    float a = bl[l * 64 + lane];
    float c = br[l * 64 + lane];
#pragma unroll
    for (int k = 0; k < 5; k++) {
      float xk = x[n * 5 + k];
      a = fmaf(xk, Wl[(l * 5 + k) * 64 + lane], a);
      c = fmaf(xk, Wr[(l * 5 + k) * 64 + lane], c);
    }
    xlb[wid * 64 + lane] = bfbits(a);
    xrb[wid * 64 + lane] = bfbits(c);
  } else {
    float* tile = (float*)smem;  // [32][33]
    int bb = b - W1T_BASE;
    int j0 = (bb % 28) * 32, k0 = (bb / 28) * 32;
    int tx = threadIdx.x & 31, ty = threadIdx.x >> 5;
    tile[ty * 33 + tx] = (j0 + tx < 800) ? W1[(k0 + ty) * 800 + j0 + tx] : 0.f;
    __syncthreads();
    W1bT[(size_t)(j0 + ty) * 800 + k0 + tx] = (__hip_bfloat16)tile[tx * 33 + ty];
  }
}

// -------- scan_a: per-block scan; also zero gsum/gsumsq ---------------------
__global__ __launch_bounds__(1024) void scan_a(const int* __restrict__ cnt,
                                               int* __restrict__ scn,
                                               int* __restrict__ btot,
                                               float* __restrict__ gsum,
                                               float* __restrict__ gsumsq) {
  int t = threadIdx.x, b = blockIdx.x;
  int i = b * 1024 + t;
  int lane = t & 63, wv = t >> 6;
  int v = (i < NL_NN) ? cnt[i] : 0;
  int sc = v;
#pragma unroll
  for (int off = 1; off < 64; off <<= 1) {
    int u = __shfl_up(sc, off);
    if (lane >= off) sc += u;
  }
  __shared__ int ws[16];
  if (lane == 63) ws[wv] = sc;
  __syncthreads();
  if (t < 16) {
    int xx = ws[t];
#pragma unroll
    for (int off = 1; off < 16; off <<= 1) {
      int u = __shfl_up(xx, off);
      if (t >= off) xx += u;
    }
    ws[t] = xx;
  }
  __syncthreads();
  int bofs = wv ? ws[wv - 1] : 0;
  if (i < NL_NN) scn[i] = bofs + sc - v;
  if (t == 0) btot[b] = ws[15];
  if (b == 200 && t < N_LAYERS * 32) {
    gsum[t] = 0.f;
    gsumsq[t] = 0.f;
  }
}

__global__ __launch_bounds__(512) void scan_b(const int* __restrict__ btot,
                                              int* __restrict__ boff) {
  int t = threadIdx.x;
  int lane = t & 63, wv = t >> 6;
  int v = (t < SCAN_BLKS) ? btot[t] : 0;
  int sc = v;
#pragma unroll
  for (int off = 1; off < 64; off <<= 1) {
    int u = __shfl_up(sc, off);
    if (lane >= off) sc += u;
  }
  __shared__ int ws[8];
  if (lane == 63) ws[wv] = sc;
  __syncthreads();
  if (t < 8) {
    int xx = ws[t];
#pragma unroll
    for (int off = 1; off < 8; off <<= 1) {
      int u = __shfl_up(xx, off);
      if (t >= off) xx += u;
    }
    ws[t] = xx;
  }
  __syncthreads();
  int bofs = wv ? ws[wv - 1] : 0;
  if (t < SCAN_BLKS) boff[t] = bofs + sc - v;
}

// ------- fill: edge-parallel, atomic-free (rank from prep); tail -> rowfin --
__global__ __launch_bounds__(1024) void fill_kernel(const int* __restrict__ ei,
                                                    const float* __restrict__ ew,
                                                    const int* __restrict__ scn,
                                                    const int* __restrict__ boff,
                                                    const int* __restrict__ rank,
                                                    int* __restrict__ rowfin,
                                                    int2* __restrict__ ep) {
  int b = blockIdx.x;
  if (b < EDGE_BLKS) {
    int idx = b * 1024 + threadIdx.x;
    if (idx >= TOTAL_E) return;
    int l = idx / N_EDGES, e = idx - l * N_EDGES;
    int src = ei[(size_t)l * 2 * N_EDGES + e];
    int dst = ei[(size_t)l * 2 * N_EDGES + N_EDGES + e];
    int g = l * N_NODES + dst;
    int pos = scn[g] + boff[g >> 10] + rank[idx];
    int2 rec;
    rec.x = src;
    rec.y = __float_as_int(ew[(size_t)l * N_EDGES + e]);
    ep[pos] = rec;
  } else {
    int i = (b - EDGE_BLKS) * 1024 + threadIdx.x;
    if (i < NL_NN) rowfin[i] = scn[i] + boff[i >> 10];
    if (i == 0) rowfin[NL_NN] = TOTAL_E;
  }
}

// ---- fused GAT layer: persistent waves, CHUNK contiguous nodes per wave ----
__global__ __launch_bounds__(256) void attn_kernel(
    const unsigned short* __restrict__ xlg, const unsigned short* __restrict__ xrg,
    const int* __restrict__ rowfin, const int2* __restrict__ ep,
    const float* __restrict__ We, const float* __restrict__ att,
    const float* __restrict__ cbias, unsigned short* __restrict__ out_pre) {
  int wave_id = blockIdx.x * 4 + (threadIdx.x >> 6);
  int lane = threadIdx.x & 63;
  int wid = wave_id * CHUNK;
  if (wid >= NL_NN) return;
  int wend = wid + CHUNK;
  if (wend > NL_NN) wend = NL_NN;

  // chunk-invariant state (reloaded only on layer boundary)
  int l = wid / N_NODES;
  int n = wid - l * N_NODES;
  float wev = We[l * 64 + lane];
  float att2v = att[l * 64 + lane] * LOG2E;
  float cbv = cbias[l * 32 + (lane & 31)];
  const unsigned short* xlb = xlg + (size_t)l * N_NODES * 64;

  int start = __builtin_amdgcn_readfirstlane(rowfin[wid]);
  for (; wid < wend; wid++, n++) {
    if (n == N_NODES) {  // layer boundary (uniform, rare)
      n = 0;
      l++;
      wev = We[l * 64 + lane];
      att2v = att[l * 64 + lane] * LOG2E;
      cbv = cbias[l * 32 + (lane & 31)];
      xlb += (size_t)N_NODES * 64;
    }
    int end = __builtin_amdgcn_readfirstlane(rowfin[wid + 1]);
    int cnt = end - start;
    int cnt64 = cnt < 64 ? cnt : 64;

    float xrn = ldbf(xrg, wid * 64 + lane);
    float xln = ldbf(xlb, n * 64 + lane);

    int rsrc = 0, rw = 0;
    if (lane < cnt64) {
      int2 rec = ep[start + lane];
      rsrc = rec.x;
      rw = rec.y;
    }

    float ewsum = __int_as_float(rw);
    ewsum = dpp_add<0xB1>(ewsum);
    ewsum = dpp_add<0x4E>(ewsum);
    ewsum = dpp_add<0x141>(ewsum);
    ewsum = dpp_add<0x140>(ewsum);
    ewsum += swz<0x401F>(ewsum);
    ewsum += __shfl_xor(ewsum, 32);

    float ssum = 0.f, acc = 0.f;

    if (cnt64 > 0) {
      int sA = __builtin_amdgcn_readlane(rsrc, 0);
      int sB = __builtin_amdgcn_readlane(rsrc, 1 & 63);
      float xa = ldbf(xlb, sA * 64 + lane);
      float xb = ldbf(xlb, sB * 64 + lane);
      for (int e = 0; e < cnt64; e += 2) {
        int sC = __builtin_amdgcn_readlane(rsrc, (e + 2) & 63);
        int sD = __builtin_amdgcn_readlane(rsrc, (e + 3) & 63);
        float xc = ldbf(xlb, sC * 64 + lane);
        float xd = ldbf(xlb, sD * 64 + lane);
        float w0 = __int_as_float(__builtin_amdgcn_readlane(rw, e));
        float w1 = __int_as_float(__builtin_amdgcn_readlane(rw, (e + 1) & 63));
        float v0 = xa + fmaf(w0, wev, xrn);
        float v1 = xb + fmaf(w1, wev, xrn);
        float lk0 = fmaxf(v0, 0.2f * v0);
        float lk1 = fmaxf(v1, 0.2f * v1);
        float p0 = lk0 * att2v;
        float p1 = lk1 * att2v;
        p0 = dpp_add<0xB1>(p0);  p1 = dpp_add<0xB1>(p1);
        p0 = dpp_add<0x4E>(p0);  p1 = dpp_add<0x4E>(p1);
        p0 = dpp_add<0x141>(p0); p1 = dpp_add<0x141>(p1);
        p0 = dpp_add<0x140>(p0); p1 = dpp_add<0x140>(p1);
        p0 += swz<0x401F>(p0);   p1 += swz<0x401F>(p1);
        float pe0 = __builtin_amdgcn_exp2f(p0);
        float pe1 = __builtin_amdgcn_exp2f(p1);
        ssum += pe0;
        acc = fmaf(xa, pe0, acc);
        if (e + 1 < cnt64) {  // uniform branch
          ssum += pe1;
          acc = fmaf(xb, pe1, acc);
        }
        xa = xc;
        xb = xd;
      }
    }
    // rare overflow path: in-degree > 64
    for (int e = start + 64; e < end; e++) {
      int2 rec = ep[e];
      int s = __builtin_amdgcn_readfirstlane(rec.x);
      float w = __int_as_float(__builtin_amdgcn_readfirstlane(rec.y));
      float xg = ldbf(xlb, s * 64 + lane);
      float v = xg + fmaf(w, wev, xrn);
      float lk = fmaxf(v, 0.2f * v);
      float p = lk * att2v;
      p = dpp_add<0xB1>(p);
      p = dpp_add<0x4E>(p);
      p = dpp_add<0x141>(p);
      p = dpp_add<0x140>(p);
      p += swz<0x401F>(p);
      float pe = __builtin_amdgcn_exp2f(p);
      ssum += pe;
      acc = fmaf(xg, pe, acc);
      ewsum += w;
    }
    // self loop: attr = mean of incoming edge attrs
    {
      float w = ewsum * __builtin_amdgcn_rcpf(fmaxf((float)cnt, 1.f));
      float v = xln + fmaf(w, wev, xrn);
      float lk = fmaxf(v, 0.2f * v);
      float p = lk * att2v;
      p = dpp_add<0xB1>(p);
      p = dpp_add<0x4E>(p);
      p = dpp_add<0x141>(p);
      p = dpp_add<0x140>(p);
      p += swz<0x401F>(p);
      float pe = __builtin_amdgcn_exp2f(p);
      ssum += pe;
      acc = fmaf(xln, pe, acc);
    }
    float outv = acc * __builtin_amdgcn_rcpf(ssum * (float)(cnt + 1));
    float o2 = outv + __shfl_xor(outv, 32);
    if (lane < 32)
      out_pre[wid * 32 + lane] = bfbits(0.5f * o2 + cbv);
    start = end;  // rowfin chaining: next node's start = this end
  }
}

// ---------------- BatchNorm stats (bf16 input) ----------------
__global__ __launch_bounds__(256) void stats_kernel(const unsigned short* __restrict__ out_pre,
                                                    float* __restrict__ gsum,
                                                    float* __restrict__ gsumsq) {
  int l = blockIdx.x >> 4, chunk = blockIdx.x & 15;
  int t = threadIdx.x;
  int c = t & 31, nsub = t >> 5;
  int n0 = chunk * 1250;
  float s1 = 0.f, s2 = 0.f;
  for (int n = n0 + nsub; n < n0 + 1250; n += 8) {
    float v = ldbf(out_pre, (l * N_NODES + n) * 32 + c);
    s1 += v; s2 += v * v;
  }
  __shared__ float l1[256], l2[256];
  l1[t] = s1; l2[t] = s2;
  __syncthreads();
  for (int off = 128; off >= 32; off >>= 1) {
    if (t < off) { l1[t] += l1[t + off]; l2[t] += l2[t + off]; }
    __syncthreads();
  }
  if (t < 32) {
    atomicAdd(&gsum[l * 32 + t], l1[t]);
    atomicAdd(&gsumsq[l * 32 + t], l2[t]);
  }
}

// ---------------- normalize + leaky relu -> bf16 [L][NPAD][32] ----------------
__global__ __launch_bounds__(256) void norm_kernel(const unsigned short* __restrict__ out_pre,
                                                   const float* __restrict__ gsum,
                                                   const float* __restrict__ gsumsq,
                                                   const float* __restrict__ gamma,
                                                   const float* __restrict__ beta,
                                                   unsigned short* __restrict__ hn) {
  int idx = blockIdx.x * 256 + threadIdx.x;
  int l = idx / (N_NODES * 8);
  int rem = idx - l * (N_NODES * 8);
  int n = rem >> 3, q = rem & 7;
  int c0 = q * 4;
  short4v v4 = *(const short4v*)(out_pre + (l * N_NODES + n) * 32 + c0);
  short4v o;
#pragma unroll
  for (int i = 0; i < 4; i++) {
    int c = c0 + i;
    float mu = gsum[l * 32 + c] * (1.f / N_NODES);
    float var = gsumsq[l * 32 + c] * (1.f / N_NODES) - mu * mu;
    float vv = __uint_as_float((unsigned)(unsigned short)v4[i] << 16);
    float v = gamma[l * 32 + c] * (vv - mu) * rsqrtf(var + EPS_BN) + beta[l * 32 + c];
    v = v > 0.f ? v : 0.01f * v;
    o[i] = (short)bfbits(v);
  }
  *(short4v*)(hn + ((size_t)l * NPAD + n) * 32 + c0) = o;
}

// ---------------- GEMM1: h[NPAD x 800] @ W1 -> relu -> bf16 h1 ----------------
__global__ __launch_bounds__(256) void gemm1_kernel(const short* __restrict__ hn,
                                                    const short* __restrict__ W1bT,
                                                    const float* __restrict__ b1,
                                                    __hip_bfloat16* __restrict__ h1b) {
  __shared__ __align__(16) short As[128 * 32];
  __shared__ __align__(16) short Bs[128 * 32];
  int t = threadIdx.x;
  int n0 = blockIdx.x * 128, m0 = blockIdx.y * 128;
  int wave = t >> 6, lane = t & 63;
  int wr = wave >> 1, wc = wave & 1;
  int mrow = lane & 15, quad = lane >> 4;
  floatx4 acc[4][4];
#pragma unroll
  for (int i = 0; i < 4; i++)
#pragma unroll
    for (int j = 0; j < 4; j++) acc[i][j] = (floatx4){0.f, 0.f, 0.f, 0.f};

  int r0 = t >> 2, s0 = t & 3;
  int r1 = (t + 256) >> 2, s1 = (t + 256) & 3;
  const short* aG0 = hn + (m0 + r0) * 32 + s0 * 8;
  const short* aG1 = hn + (m0 + r1) * 32 + s1 * 8;
  const short* bG0 = W1bT + (n0 + r0) * 800 + s0 * 8;
  const short* bG1 = W1bT + (n0 + r1) * 800 + s1 * 8;
  const int ak = NPAD * 32;
  short* aD0 = As + wave * 512;
  short* aD1 = As + 2048 + wave * 512;
  short* bD0 = Bs + wave * 512;
  short* bD1 = Bs + 2048 + wave * 512;

  for (int kt = 0; kt < 25; kt++) {
    gl_lds16(aG0, aD0);
    gl_lds16(aG1, aD1);
    gl_lds16(bG0, bD0);
    gl_lds16(bG1, bD1);
    aG0 += ak; aG1 += ak; bG0 += 32; bG1 += 32;
    __syncthreads();
    short8 af[4], bfr[4];
#pragma unroll
    for (int i = 0; i < 4; i++)
      af[i] = *(const short8*)(&As[(wr * 64 + i * 16 + mrow) * 32 + quad * 8]);
#pragma unroll
    for (int j = 0; j < 4; j++)
      bfr[j] = *(const short8*)(&Bs[(wc * 64 + j * 16 + mrow) * 32 + quad * 8]);
#pragma unroll
    for (int i = 0; i < 4; i++)
#pragma unroll
      for (int j = 0; j < 4; j++)
        acc[i][j] = __builtin_amdgcn_mfma_f32_16x16x32_bf16(af[i], bfr[j], acc[i][j], 0, 0, 0);
    __syncthreads();
  }

#pragma unroll
  for (int i = 0; i < 4; i++) {
#pragma unroll
    for (int j = 0; j < 4; j++) {
#pragma unroll
      for (int r = 0; r < 4; r++) {
        int row = m0 + wr * 64 + i * 16 + quad * 4 + r;
        int col = n0 + wc * 64 + j * 16 + mrow;
        if (col < 800) {
          float v = acc[i][j][r] + b1[col];
          v = fmaxf(v, 0.f);
          h1b[(size_t)row * 800 + col] = (__hip_bfloat16)v;
        }
      }
    }
  }
}

// ---------------- GEMM2: h1[20000 x 800] @ W2[800 x 5] + b2 ----------------
__global__ __launch_bounds__(256) void gemm2_kernel(const __hip_bfloat16* __restrict__ h1b,
                                                    const float* __restrict__ W2,
                                                    const float* __restrict__ b2,
                                                    float* __restrict__ out) {
  int wid = blockIdx.x * 4 + (threadIdx.x >> 6);
  int lane = threadIdx.x & 63;
  if (wid >= N_NODES) return;
  const __hip_bfloat16* row = h1b + (size_t)wid * 800;
  float a[5] = {0.f, 0.f, 0.f, 0.f, 0.f};
  for (int k = lane * 2; k < 800; k += 128) {
    float a0 = (float)row[k], a1 = (float)row[k + 1];
#pragma unroll
    for (int j = 0; j < 5; j++) a[j] += a0 * W2[k * 5 + j] + a1 * W2[(k + 1) * 5 + j];
  }
#pragma unroll
  for (int j = 0; j < 5; j++) {
    a[j] += __shfl_xor(a[j], 32);
    a[j] += __shfl_xor(a[j], 16);
    a[j] += __shfl_xor(a[j], 8);
    a[j] += __shfl_xor(a[j], 4);
    a[j] += __shfl_xor(a[j], 2);
    a[j] += __shfl_xor(a[j], 1);
  }
  if (lane == 0) {
#pragma unroll
    for (int j = 0; j < 5; j++) out[wid * 5 + j] = a[j] + b2[j];
  }
}

extern "C" void kernel_launch(void* const* d_in, const int* in_sizes, int n_in,
                              void* d_out, int out_size, void* d_ws, size_t ws_size,
                              hipStream_t stream) {
  const float* x    = (const float*)d_in[0];
  const int*   ei   = (const int*)d_in[1];
  const float* ew   = (const float*)d_in[2];
  const float* Wl   = (const float*)d_in[3];
  const float* bl   = (const float*)d_in[4];
  const float* Wr   = (const float*)d_in[5];
  const float* br   = (const float*)d_in[6];
  const float* We   = (const float*)d_in[7];
  const float* att  = (const float*)d_in[8];
  const float* cb   = (const float*)d_in[9];
  const float* gam  = (const float*)d_in[10];
  const float* bet  = (const float*)d_in[11];
  const float* W1   = (const float*)d_in[12];
  const float* b1   = (const float*)d_in[13];
  const float* W2   = (const float*)d_in[14];
  const float* b2   = (const float*)d_in[15];

  char* ws = (char*)d_ws;
  size_t off = 0;
  auto alloc = [&](size_t bytes) {
    void* p = ws + off;
    off = (off + bytes + 255) & ~(size_t)255;
    return p;
  };
  int* cnt     = (int*)alloc((size_t)NL_NN * 4);
  int* scn     = (int*)alloc((size_t)NL_NN * 4);
  int* btot    = (int*)alloc(SCAN_BLKS * 4);
  int* boff    = (int*)alloc(SCAN_BLKS * 4);
  int* rank    = (int*)alloc((size_t)TOTAL_E * 4);
  int* rowfin  = (int*)alloc((size_t)(NL_NN + 1) * 4);
  int2* ep     = (int2*)alloc((size_t)TOTAL_E * 8);
  unsigned short* out_pre = (unsigned short*)alloc((size_t)NL_NN * 32 * 2);
  float* gsum   = (float*)alloc(N_LAYERS * 32 * 4);
  float* gsumsq = (float*)alloc(N_LAYERS * 32 * 4);
  unsigned short* xlb = (unsigned short*)alloc((size_t)NL_NN * 64 * 2);
  unsigned short* xrb = (unsigned short*)alloc((size_t)NL_NN * 64 * 2);
  __hip_bfloat16* w1t = (__hip_bfloat16*)alloc((size_t)896 * 800 * 2);
  unsigned short* hn  = (unsigned short*)xlb;  // alias: xlb dead after attn
  __hip_bfloat16* h1b = (__hip_bfloat16*)xrb;  // alias: xrb dead after attn

  prep_kernel<<<PREP_BLKS, 1024, 0, stream>>>(ei, x, Wl, bl, Wr, br, W1,
                                              cnt, rank, xlb, xrb, w1t);
  scan_a<<<SCAN_BLKS, 1024, 0, stream>>>(cnt, scn, btot, gsum, gsumsq);
  scan_b<<<1, 512, 0, stream>>>(btot, boff);
  fill_kernel<<<FILL_BLKS, 1024, 0, stream>>>(ei, ew, scn, boff, rank, rowfin, ep);
  attn_kernel<<<ATTN_BLKS, 256, 0, stream>>>(
      xlb, xrb, rowfin, ep, We, att, cb, out_pre);
  stats_kernel<<<N_LAYERS * 16, 256, 0, stream>>>(out_pre, gsum, gsumsq);
  norm_kernel<<<(NL_NN * 8) / 256, 256, 0, stream>>>(
      out_pre, gsum, gsumsq, gam, bet, hn);
  gemm1_kernel<<<dim3(7, 157), 256, 0, stream>>>(
      (const short*)hn, (const short*)w1t, b1, h1b);
  gemm2_kernel<<<5000, 256, 0, stream>>>(h1b, W2, b2, (float*)d_out);
}

// Round 17
// 563.167 us; speedup vs baseline: 1.0822x; 1.0822x over previous
//
#include <hip/hip_runtime.h>
#include <hip/hip_bf16.h>

#define N_NODES 20000
#define N_EDGES 100000
#define N_LAYERS 25
#define NPAD 20096   // 157*128
#define EPS_BN 1e-5f
#define LOG2E 1.44269504088896340736f
#define NL_NN (N_LAYERS * N_NODES)          // 500000
#define TOTAL_E (N_LAYERS * N_EDGES)        // 2500000
#define SCAN_BLKS ((NL_NN + 1023) / 1024)   // 489
#define QUARTER_N 5000
#define CNT_BLKS (N_LAYERS * 4)             // 100
#define XLR_BASE CNT_BLKS                   // 100
#define XLR_BLKS (NL_NN / 16)               // 31250
#define W1T_BASE (XLR_BASE + XLR_BLKS)      // 31350
#define PREP_BLKS (W1T_BASE + 700)          // 32050
#define EDGE_BLKS ((TOTAL_E + 1023) / 1024) // 2442
#define FILL_BLKS (EDGE_BLKS + SCAN_BLKS)
#define NGRP 14                             // 7 col-blocks x 2 wc halves

typedef short short8 __attribute__((ext_vector_type(8)));
typedef short short4v __attribute__((ext_vector_type(4)));
typedef float floatx4 __attribute__((ext_vector_type(4)));

template <int PAT>
__device__ __forceinline__ float swz(float v) {
  return __int_as_float(__builtin_amdgcn_ds_swizzle(__float_as_int(v), PAT));
}

template <int CTRL>
__device__ __forceinline__ float dpp_add(float v) {
  int r = __builtin_amdgcn_update_dpp(0, __float_as_int(v), CTRL, 0xF, 0xF, true);
  return v + __int_as_float(r);
}

// int index on purpose: 32-bit address math
__device__ __forceinline__ float ldbf(const unsigned short* __restrict__ p, int idx) {
  return __uint_as_float((unsigned)p[idx] << 16);
}

__device__ __forceinline__ unsigned short bfbits(float v) {
  return __builtin_bit_cast(unsigned short, (__hip_bfloat16)v);
}

// async global->LDS, 16B per lane; LDS dest = wave-uniform base + lane*16
__device__ __forceinline__ void gl_lds16(const short* g, short* l) {
  __builtin_amdgcn_global_load_lds(
      (const __attribute__((address_space(1))) void*)g,
      (__attribute__((address_space(3))) void*)l, 16, 0, 0);
}

// --- prep: count (LDS histogram, captures per-edge rank) + xlr + w1t --------
__global__ __launch_bounds__(1024) void prep_kernel(
    const int* __restrict__ ei, const float* __restrict__ x,
    const float* __restrict__ Wl, const float* __restrict__ bl,
    const float* __restrict__ Wr, const float* __restrict__ br,
    const float* __restrict__ W1, int* __restrict__ cnt,
    int* __restrict__ rank,
    unsigned short* __restrict__ xlb, unsigned short* __restrict__ xrb,
    __hip_bfloat16* __restrict__ W1bT) {
  __shared__ int smem[QUARTER_N];  // 20 KB (count hist); w1t reuses as float tile
  int b = blockIdx.x;
  if (b < XLR_BASE) {
    int l = b >> 2, base = (b & 3) * QUARTER_N;
    for (int i = threadIdx.x; i < QUARTER_N; i += 1024) smem[i] = 0;
    __syncthreads();
    const int* dstp = ei + (size_t)l * 2 * N_EDGES + N_EDGES;
    int* rkp = rank + l * N_EDGES;
    for (int e = threadIdx.x; e < N_EDGES; e += 1024) {
      int d = dstp[e] - base;
      if ((unsigned)d < (unsigned)QUARTER_N) rkp[e] = atomicAdd(&smem[d], 1);
    }
    __syncthreads();
    int* outp = cnt + l * N_NODES + base;
    for (int i = threadIdx.x; i < QUARTER_N; i += 1024) outp[i] = smem[i];
  } else if (b < W1T_BASE) {
    int wid = (b - XLR_BASE) * 16 + (threadIdx.x >> 6);
    int lane = threadIdx.x & 63;
    int l = wid / N_NODES, n = wid - l * N_NODES;
    float a = bl[l * 64 + lane];
    float c = br[l * 64 + lane];
#pragma unroll
    for (int k = 0; k < 5; k++) {
      float xk = x[n * 5 + k];
      a = fmaf(xk, Wl[(l * 5 + k) * 64 + lane], a);
      c = fmaf(xk, Wr[(l * 5 + k) * 64 + lane], c);
    }
    xlb[wid * 64 + lane] = bfbits(a);
    xrb[wid * 64 + lane] = bfbits(c);
  } else {
    float* tile = (float*)smem;  // [32][33]
    int bb = b - W1T_BASE;
    int j0 = (bb % 28) * 32, k0 = (bb / 28) * 32;
    int tx = threadIdx.x & 31, ty = threadIdx.x >> 5;
    tile[ty * 33 + tx] = (j0 + tx < 800) ? W1[(k0 + ty) * 800 + j0 + tx] : 0.f;
    __syncthreads();
    W1bT[(size_t)(j0 + ty) * 800 + k0 + tx] = (__hip_bfloat16)tile[tx * 33 + ty];
  }
}

// -------- scan_a: per-block scan; also zero gsum/gsumsq ---------------------
__global__ __launch_bounds__(1024) void scan_a(const int* __restrict__ cnt,
                                               int* __restrict__ scn,
                                               int* __restrict__ btot,
                                               float* __restrict__ gsum,
                                               float* __restrict__ gsumsq) {
  int t = threadIdx.x, b = blockIdx.x;
  int i = b * 1024 + t;
  int lane = t & 63, wv = t >> 6;
  int v = (i < NL_NN) ? cnt[i] : 0;
  int sc = v;
#pragma unroll
  for (int off = 1; off < 64; off <<= 1) {
    int u = __shfl_up(sc, off);
    if (lane >= off) sc += u;
  }
  __shared__ int ws[16];
  if (lane == 63) ws[wv] = sc;
  __syncthreads();
  if (t < 16) {
    int xx = ws[t];
#pragma unroll
    for (int off = 1; off < 16; off <<= 1) {
      int u = __shfl_up(xx, off);
      if (t >= off) xx += u;
    }
    ws[t] = xx;
  }
  __syncthreads();
  int bofs = wv ? ws[wv - 1] : 0;
  if (i < NL_NN) scn[i] = bofs + sc - v;
  if (t == 0) btot[b] = ws[15];
  if (b == 200 && t < N_LAYERS * 32) {
    gsum[t] = 0.f;
    gsumsq[t] = 0.f;
  }
}

__global__ __launch_bounds__(512) void scan_b(const int* __restrict__ btot,
                                              int* __restrict__ boff) {
  int t = threadIdx.x;
  int lane = t & 63, wv = t >> 6;
  int v = (t < SCAN_BLKS) ? btot[t] : 0;
  int sc = v;
#pragma unroll
  for (int off = 1; off < 64; off <<= 1) {
    int u = __shfl_up(sc, off);
    if (lane >= off) sc += u;
  }
  __shared__ int ws[8];
  if (lane == 63) ws[wv] = sc;
  __syncthreads();
  if (t < 8) {
    int xx = ws[t];
#pragma unroll
    for (int off = 1; off < 8; off <<= 1) {
      int u = __shfl_up(xx, off);
      if (t >= off) xx += u;
    }
    ws[t] = xx;
  }
  __syncthreads();
  int bofs = wv ? ws[wv - 1] : 0;
  if (t < SCAN_BLKS) boff[t] = bofs + sc - v;
}

// ------- fill: edge-parallel, atomic-free (rank from prep); tail -> rowfin --
__global__ __launch_bounds__(1024) void fill_kernel(const int* __restrict__ ei,
                                                    const float* __restrict__ ew,
                                                    const int* __restrict__ scn,
                                                    const int* __restrict__ boff,
                                                    const int* __restrict__ rank,
                                                    int* __restrict__ rowfin,
                                                    int2* __restrict__ ep) {
  int b = blockIdx.x;
  if (b < EDGE_BLKS) {
    int idx = b * 1024 + threadIdx.x;
    if (idx >= TOTAL_E) return;
    int l = idx / N_EDGES, e = idx - l * N_EDGES;
    int src = ei[(size_t)l * 2 * N_EDGES + e];
    int dst = ei[(size_t)l * 2 * N_EDGES + N_EDGES + e];
    int g = l * N_NODES + dst;
    int pos = scn[g] + boff[g >> 10] + rank[idx];
    int2 rec;
    rec.x = src;
    rec.y = __float_as_int(ew[(size_t)l * N_EDGES + e]);
    ep[pos] = rec;
  } else {
    int i = (b - EDGE_BLKS) * 1024 + threadIdx.x;
    if (i < NL_NN) rowfin[i] = scn[i] + boff[i >> 10];
    if (i == 0) rowfin[NL_NN] = TOTAL_E;
  }
}

// ---------------- fused GAT layer (1 wave per (layer,node), paired edges) ----
__global__ __launch_bounds__(256) void attn_kernel(
    const unsigned short* __restrict__ xlg, const unsigned short* __restrict__ xrg,
    const int* __restrict__ rowfin, const int2* __restrict__ ep,
    const float* __restrict__ We, const float* __restrict__ att,
    const float* __restrict__ cbias, unsigned short* __restrict__ out_pre) {
  int wid = blockIdx.x * 4 + (threadIdx.x >> 6);
  int lane = threadIdx.x & 63;
  int l = wid / N_NODES, n = wid - l * N_NODES;

  const unsigned short* xlb = xlg + (size_t)l * N_NODES * 64;
  float wev = We[l * 64 + lane];
  float att2v = att[l * 64 + lane] * LOG2E;

  float xrn = ldbf(xrg, wid * 64 + lane);
  float xln = ldbf(xlb, n * 64 + lane);

  int start = __builtin_amdgcn_readfirstlane(rowfin[wid]);
  int end   = __builtin_amdgcn_readfirstlane(rowfin[wid + 1]);
  int cnt = end - start;
  int cnt64 = cnt < 64 ? cnt : 64;

  int rsrc = 0, rw = 0;
  if (lane < cnt64) {
    int2 rec = ep[start + lane];
    rsrc = rec.x;
    rw = rec.y;
  }

  float ewsum = __int_as_float(rw);
  ewsum = dpp_add<0xB1>(ewsum);
  ewsum = dpp_add<0x4E>(ewsum);
  ewsum = dpp_add<0x141>(ewsum);
  ewsum = dpp_add<0x140>(ewsum);
  ewsum += swz<0x401F>(ewsum);
  ewsum += __shfl_xor(ewsum, 32);

  float ssum = 0.f, acc = 0.f;

  if (cnt64 > 0) {
    int sA = __builtin_amdgcn_readlane(rsrc, 0);
    int sB = __builtin_amdgcn_readlane(rsrc, 1 & 63);
    float xa = ldbf(xlb, sA * 64 + lane);
    float xb = ldbf(xlb, sB * 64 + lane);
    for (int e = 0; e < cnt64; e += 2) {
      int sC = __builtin_amdgcn_readlane(rsrc, (e + 2) & 63);
      int sD = __builtin_amdgcn_readlane(rsrc, (e + 3) & 63);
      float xc = ldbf(xlb, sC * 64 + lane);
      float xd = ldbf(xlb, sD * 64 + lane);
      float w0 = __int_as_float(__builtin_amdgcn_readlane(rw, e));
      float w1 = __int_as_float(__builtin_amdgcn_readlane(rw, (e + 1) & 63));
      float v0 = xa + fmaf(w0, wev, xrn);
      float v1 = xb + fmaf(w1, wev, xrn);
      float lk0 = fmaxf(v0, 0.2f * v0);
      float lk1 = fmaxf(v1, 0.2f * v1);
      float p0 = lk0 * att2v;
      float p1 = lk1 * att2v;
      p0 = dpp_add<0xB1>(p0);  p1 = dpp_add<0xB1>(p1);
      p0 = dpp_add<0x4E>(p0);  p1 = dpp_add<0x4E>(p1);
      p0 = dpp_add<0x141>(p0); p1 = dpp_add<0x141>(p1);
      p0 = dpp_add<0x140>(p0); p1 = dpp_add<0x140>(p1);
      p0 += swz<0x401F>(p0);   p1 += swz<0x401F>(p1);
      float pe0 = __builtin_amdgcn_exp2f(p0);
      float pe1 = __builtin_amdgcn_exp2f(p1);
      ssum += pe0;
      acc = fmaf(xa, pe0, acc);
      if (e + 1 < cnt64) {
        ssum += pe1;
        acc = fmaf(xb, pe1, acc);
      }
      xa = xc;
      xb = xd;
    }
  }
  for (int e = start + 64; e < end; e++) {
    int2 rec = ep[e];
    int s = __builtin_amdgcn_readfirstlane(rec.x);
    float w = __int_as_float(__builtin_amdgcn_readfirstlane(rec.y));
    float xg = ldbf(xlb, s * 64 + lane);
    float v = xg + fmaf(w, wev, xrn);
    float lk = fmaxf(v, 0.2f * v);
    float p = lk * att2v;
    p = dpp_add<0xB1>(p);
    p = dpp_add<0x4E>(p);
    p = dpp_add<0x141>(p);
    p = dpp_add<0x140>(p);
    p += swz<0x401F>(p);
    float pe = __builtin_amdgcn_exp2f(p);
    ssum += pe;
    acc = fmaf(xg, pe, acc);
    ewsum += w;
  }
  {
    float w = ewsum * __builtin_amdgcn_rcpf(fmaxf((float)cnt, 1.f));
    float v = xln + fmaf(w, wev, xrn);
    float lk = fmaxf(v, 0.2f * v);
    float p = lk * att2v;
    p = dpp_add<0xB1>(p);
    p = dpp_add<0x4E>(p);
    p = dpp_add<0x141>(p);
    p = dpp_add<0x140>(p);
    p += swz<0x401F>(p);
    float pe = __builtin_amdgcn_exp2f(p);
    ssum += pe;
    acc = fmaf(xln, pe, acc);
  }
  float outv = acc * __builtin_amdgcn_rcpf(ssum * (float)(cnt + 1));
  float o2 = outv + __shfl_xor(outv, 32);
  if (lane < 32)
    out_pre[wid * 32 + lane] = bfbits(0.5f * o2 + cbias[l * 32 + lane]);
}

// ---------------- BatchNorm stats (bf16 input) ----------------
__global__ __launch_bounds__(256) void stats_kernel(const unsigned short* __restrict__ out_pre,
                                                    float* __restrict__ gsum,
                                                    float* __restrict__ gsumsq) {
  int l = blockIdx.x >> 4, chunk = blockIdx.x & 15;
  int t = threadIdx.x;
  int c = t & 31, nsub = t >> 5;
  int n0 = chunk * 1250;
  float s1 = 0.f, s2 = 0.f;
  for (int n = n0 + nsub; n < n0 + 1250; n += 8) {
    float v = ldbf(out_pre, (l * N_NODES + n) * 32 + c);
    s1 += v; s2 += v * v;
  }
  __shared__ float l1[256], l2[256];
  l1[t] = s1; l2[t] = s2;
  __syncthreads();
  for (int off = 128; off >= 32; off >>= 1) {
    if (t < off) { l1[t] += l1[t + off]; l2[t] += l2[t + off]; }
    __syncthreads();
  }
  if (t < 32) {
    atomicAdd(&gsum[l * 32 + t], l1[t]);
    atomicAdd(&gsumsq[l * 32 + t], l2[t]);
  }
}

// ---------------- normalize + leaky relu -> bf16 [L][NPAD][32] ----------------
__global__ __launch_bounds__(256) void norm_kernel(const unsigned short* __restrict__ out_pre,
                                                   const float* __restrict__ gsum,
                                                   const float* __restrict__ gsumsq,
                                                   const float* __restrict__ gamma,
                                                   const float* __restrict__ beta,
                                                   unsigned short* __restrict__ hn) {
  int idx = blockIdx.x * 256 + threadIdx.x;
  int l = idx / (N_NODES * 8);
  int rem = idx - l * (N_NODES * 8);
  int n = rem >> 3, q = rem & 7;
  int c0 = q * 4;
  short4v v4 = *(const short4v*)(out_pre + (l * N_NODES + n) * 32 + c0);
  short4v o;
#pragma unroll
  for (int i = 0; i < 4; i++) {
    int c = c0 + i;
    float mu = gsum[l * 32 + c] * (1.f / N_NODES);
    float var = gsumsq[l * 32 + c] * (1.f / N_NODES) - mu * mu;
    float vv = __uint_as_float((unsigned)(unsigned short)v4[i] << 16);
    float v = gamma[l * 32 + c] * (vv - mu) * rsqrtf(var + EPS_BN) + beta[l * 32 + c];
    v = v > 0.f ? v : 0.01f * v;
    o[i] = (short)bfbits(v);
  }
  *(short4v*)(hn + ((size_t)l * NPAD + n) * 32 + c0) = o;
}

// --- GEMM1: h @ W1 -> relu -> per-colgroup 5-dot partials (non-atomic) ------
// each (block, wc) writes disjoint p[row][group][5]; group = blockIdx.x*2+wc
__global__ __launch_bounds__(256) void gemm1_kernel(const short* __restrict__ hn,
                                                    const short* __restrict__ W1bT,
                                                    const float* __restrict__ b1,
                                                    const float* __restrict__ W2,
                                                    float* __restrict__ p) {
  __shared__ __align__(16) short As[128 * 32];
  __shared__ __align__(16) short Bs[128 * 32];
  int t = threadIdx.x;
  int n0 = blockIdx.x * 128, m0 = blockIdx.y * 128;
  int wave = t >> 6, lane = t & 63;
  int wr = wave >> 1, wc = wave & 1;
  int mrow = lane & 15, quad = lane >> 4;
  floatx4 acc[4][4];
#pragma unroll
  for (int i = 0; i < 4; i++)
#pragma unroll
    for (int j = 0; j < 4; j++) acc[i][j] = (floatx4){0.f, 0.f, 0.f, 0.f};

  int r0 = t >> 2, s0 = t & 3;
  int r1 = (t + 256) >> 2, s1 = (t + 256) & 3;
  const short* aG0 = hn + (m0 + r0) * 32 + s0 * 8;
  const short* aG1 = hn + (m0 + r1) * 32 + s1 * 8;
  const short* bG0 = W1bT + (n0 + r0) * 800 + s0 * 8;
  const short* bG1 = W1bT + (n0 + r1) * 800 + s1 * 8;
  const int ak = NPAD * 32;
  short* aD0 = As + wave * 512;
  short* aD1 = As + 2048 + wave * 512;
  short* bD0 = Bs + wave * 512;
  short* bD1 = Bs + 2048 + wave * 512;

  for (int kt = 0; kt < 25; kt++) {
    gl_lds16(aG0, aD0);
    gl_lds16(aG1, aD1);
    gl_lds16(bG0, bD0);
    gl_lds16(bG1, bD1);
    aG0 += ak; aG1 += ak; bG0 += 32; bG1 += 32;
    __syncthreads();
    short8 af[4], bfr[4];
#pragma unroll
    for (int i = 0; i < 4; i++)
      af[i] = *(const short8*)(&As[(wr * 64 + i * 16 + mrow) * 32 + quad * 8]);
#pragma unroll
    for (int j = 0; j < 4; j++)
      bfr[j] = *(const short8*)(&Bs[(wc * 64 + j * 16 + mrow) * 32 + quad * 8]);
#pragma unroll
    for (int i = 0; i < 4; i++)
#pragma unroll
      for (int j = 0; j < 4; j++)
        acc[i][j] = __builtin_amdgcn_mfma_f32_16x16x32_bf16(af[i], bfr[j], acc[i][j], 0, 0, 0);
    __syncthreads();
  }

  // epilogue: relu+bias, 5-dot with W2, 16-lane DPP reduce, disjoint stores
  float w2v[4][5];
  float b1v[4];
#pragma unroll
  for (int j = 0; j < 4; j++) {
    int col = n0 + wc * 64 + j * 16 + mrow;
    bool ok = col < 800;
    b1v[j] = ok ? b1[col] : 0.f;
#pragma unroll
    for (int jj = 0; jj < 5; jj++) w2v[j][jj] = ok ? W2[col * 5 + jj] : 0.f;
  }
  int grp = blockIdx.x * 2 + wc;
#pragma unroll
  for (int i = 0; i < 4; i++) {
#pragma unroll
    for (int r = 0; r < 4; r++) {
      float s[5] = {0.f, 0.f, 0.f, 0.f, 0.f};
#pragma unroll
      for (int j = 0; j < 4; j++) {
        float v = fmaxf(acc[i][j][r] + b1v[j], 0.f);
#pragma unroll
        for (int jj = 0; jj < 5; jj++) s[jj] = fmaf(v, w2v[j][jj], s[jj]);
      }
#pragma unroll
      for (int jj = 0; jj < 5; jj++) {
        s[jj] = dpp_add<0xB1>(s[jj]);
        s[jj] = dpp_add<0x4E>(s[jj]);
        s[jj] = dpp_add<0x141>(s[jj]);
        s[jj] = dpp_add<0x140>(s[jj]);
      }
      int row = m0 + wr * 64 + i * 16 + quad * 4 + r;
      if (mrow == 0) {
#pragma unroll
        for (int jj = 0; jj < 5; jj++)
          p[(row * NGRP + grp) * 5 + jj] = s[jj];
      }
    }
  }
}

// ---- gemm2r: out[row][jj] = b2[jj] + sum_g p[row][g][jj] -------------------
__global__ __launch_bounds__(256) void gemm2r_kernel(const float* __restrict__ p,
                                                     const float* __restrict__ b2,
                                                     float* __restrict__ out) {
  int idx = blockIdx.x * 256 + threadIdx.x;
  if (idx >= N_NODES * 5) return;
  int row = idx / 5, jj = idx - row * 5;
  float s = b2[jj];
#pragma unroll
  for (int g = 0; g < NGRP; g++) s += p[(row * NGRP + g) * 5 + jj];
  out[idx] = s;
}

extern "C" void kernel_launch(void* const* d_in, const int* in_sizes, int n_in,
                              void* d_out, int out_size, void* d_ws, size_t ws_size,
                              hipStream_t stream) {
  const float* x    = (const float*)d_in[0];
  const int*   ei   = (const int*)d_in[1];
  const float* ew   = (const float*)d_in[2];
  const float* Wl   = (const float*)d_in[3];
  const float* bl   = (const float*)d_in[4];
  const float* Wr   = (const float*)d_in[5];
  const float* br   = (const float*)d_in[6];
  const float* We   = (const float*)d_in[7];
  const float* att  = (const float*)d_in[8];
  const float* cb   = (const float*)d_in[9];
  const float* gam  = (const float*)d_in[10];
  const float* bet  = (const float*)d_in[11];
  const float* W1   = (const float*)d_in[12];
  const float* b1   = (const float*)d_in[13];
  const float* W2   = (const float*)d_in[14];
  const float* b2   = (const float*)d_in[15];

  char* ws = (char*)d_ws;
  size_t off = 0;
  auto alloc = [&](size_t bytes) {
    void* p = ws + off;
    off = (off + bytes + 255) & ~(size_t)255;
    return p;
  };
  int* cnt     = (int*)alloc((size_t)NL_NN * 4);
  int* scn     = (int*)alloc((size_t)NL_NN * 4);
  int* btot    = (int*)alloc(SCAN_BLKS * 4);
  int* boff    = (int*)alloc(SCAN_BLKS * 4);
  int* rank    = (int*)alloc((size_t)TOTAL_E * 4);
  int* rowfin  = (int*)alloc((size_t)(NL_NN + 1) * 4);
  int2* ep     = (int2*)alloc((size_t)TOTAL_E * 8);
  unsigned short* out_pre = (unsigned short*)alloc((size_t)NL_NN * 32 * 2);
  float* gsum   = (float*)alloc(N_LAYERS * 32 * 4);
  float* gsumsq = (float*)alloc(N_LAYERS * 32 * 4);
  unsigned short* xlb = (unsigned short*)alloc((size_t)NL_NN * 64 * 2);
  unsigned short* xrb = (unsigned short*)alloc((size_t)NL_NN * 64 * 2);
  __hip_bfloat16* w1t = (__hip_bfloat16*)alloc((size_t)896 * 800 * 2);
  float* pbuf = (float*)alloc((size_t)NPAD * NGRP * 5 * 4);  // 5.6 MB partials
  unsigned short* hn  = (unsigned short*)xlb;  // alias: xlb dead after attn

  prep_kernel<<<PREP_BLKS, 1024, 0, stream>>>(ei, x, Wl, bl, Wr, br, W1,
                                              cnt, rank, xlb, xrb, w1t);
  scan_a<<<SCAN_BLKS, 1024, 0, stream>>>(cnt, scn, btot, gsum, gsumsq);
  scan_b<<<1, 512, 0, stream>>>(btot, boff);
  fill_kernel<<<FILL_BLKS, 1024, 0, stream>>>(ei, ew, scn, boff, rank, rowfin, ep);
  attn_kernel<<<NL_NN / 4, 256, 0, stream>>>(
      xlb, xrb, rowfin, ep, We, att, cb, out_pre);
  stats_kernel<<<N_LAYERS * 16, 256, 0, stream>>>(out_pre, gsum, gsumsq);
  norm_kernel<<<(NL_NN * 8) / 256, 256, 0, stream>>>(
      out_pre, gsum, gsumsq, gam, bet, hn);
  gemm1_kernel<<<dim3(7, 157), 256, 0, stream>>>(
      (const short*)hn, (const short*)w1t, b1, W2, pbuf);
  gemm2r_kernel<<<(N_NODES * 5 + 255) / 256, 256, 0, stream>>>(
      pbuf, b2, (float*)d_out);
}